// Round 3
// baseline (50.625 us; speedup 1.0000x reference)
//
#include <hip/hip_runtime.h>

#define LPTS  2048   // points per row
#define NSEG  2047   // increments per row
#define TPR   128    // threads per row (2 waves)
#define STEPS 16     // segments per thread
#define NBATCH 2048

// a := a ⊗ sig(segment with increment v)   [depth-3 truncated tensor algebra]
__device__ __forceinline__ void chen_step(float a[14], float vx, float vy) {
    const float a1x = a[0], a1y = a[1];
    const float a2xx = a[2], a2xy = a[3], a2yx = a[4], a2yy = a[5];
    const float qxx = 0.5f * vx * vx;
    const float qxy = 0.5f * vx * vy;
    const float qyy = 0.5f * vy * vy;
    const float wx = fmaf(vx, (1.0f / 3.0f), a1x);
    const float wy = fmaf(vy, (1.0f / 3.0f), a1y);
    a[6]  += a2xx * vx + wx * qxx;
    a[7]  += a2xx * vy + wx * qxy;
    a[8]  += a2xy * vx + wx * qxy;
    a[9]  += a2xy * vy + wx * qyy;
    a[10] += a2yx * vx + wy * qxx;
    a[11] += a2yx * vy + wy * qxy;
    a[12] += a2yy * vx + wy * qxy;
    a[13] += a2yy * vy + wy * qyy;
    const float ux = fmaf(vx, 0.5f, a1x);
    const float uy = fmaf(vy, 0.5f, a1y);
    a[2] = fmaf(ux, vx, a[2]);
    a[3] = fmaf(ux, vy, a[3]);
    a[4] = fmaf(uy, vx, a[4]);
    a[5] = fmaf(uy, vy, a[5]);
    a[0] = a1x + vx;
    a[1] = a1y + vy;
}

// b := a ⊗ b  (a earlier, b later). Chen's identity, depth 3.
__device__ __forceinline__ void chen_combine(const float a[14], float b[14]) {
    float c[14];
    c[0] = a[0] + b[0];
    c[1] = a[1] + b[1];
    c[2] = a[2] + a[0] * b[0] + b[2];
    c[3] = a[3] + a[0] * b[1] + b[3];
    c[4] = a[4] + a[1] * b[0] + b[4];
    c[5] = a[5] + a[1] * b[1] + b[5];
    c[6]  = a[6]  + a[2] * b[0] + a[0] * b[2] + b[6];
    c[7]  = a[7]  + a[2] * b[1] + a[0] * b[3] + b[7];
    c[8]  = a[8]  + a[3] * b[0] + a[0] * b[4] + b[8];
    c[9]  = a[9]  + a[3] * b[1] + a[0] * b[5] + b[9];
    c[10] = a[10] + a[4] * b[0] + a[1] * b[2] + b[10];
    c[11] = a[11] + a[4] * b[1] + a[1] * b[3] + b[11];
    c[12] = a[12] + a[5] * b[0] + a[1] * b[4] + b[12];
    c[13] = a[13] + a[5] * b[1] + a[1] * b[5] + b[13];
#pragma unroll
    for (int i = 0; i < 14; ++i) b[i] = c[i];
}

// pointwise MLP 1 -> 8 -> 2 (ReLU between)
__device__ __forceinline__ void augment(float x,
                                        const float W1[8], const float B1[8],
                                        const float W2x[8], const float W2y[8],
                                        float B2x, float B2y,
                                        float& px, float& py) {
    float ox = B2x, oy = B2y;
#pragma unroll
    for (int c = 0; c < 8; ++c) {
        float h = fmaxf(fmaf(W1[c], x, B1[c]), 0.0f);
        ox = fmaf(W2x[c], h, ox);
        oy = fmaf(W2y[c], h, oy);
    }
    px = ox;
    py = oy;
}

__global__ __launch_bounds__(TPR, 4) void sig_scan_kernel(
    const float* __restrict__ x, const float* __restrict__ w1,
    const float* __restrict__ b1, const float* __restrict__ w2,
    const float* __restrict__ b2, const float* __restrict__ wout,
    float* __restrict__ out) {
    __shared__ float wsum[15];  // wave-0 total signature

    const int t = threadIdx.x;
    const int lane = t & 63;
    const int wv = t >> 6;  // 0 or 1
    const int brow = blockIdx.x;
    const float* __restrict__ xrow = x + (size_t)brow * LPTS;

    // ---- load this thread's 17 points (16 owned + 1 boundary) ----
    const int n0 = t * STEPS;
    float xv[STEPS + 1];
#pragma unroll
    for (int q = 0; q < 4; ++q) {
        const float4 v4 = *reinterpret_cast<const float4*>(xrow + n0 + 4 * q);
        xv[4 * q + 0] = v4.x;
        xv[4 * q + 1] = v4.y;
        xv[4 * q + 2] = v4.z;
        xv[4 * q + 3] = v4.w;
    }
    const int ib = (n0 + STEPS > LPTS - 1) ? (LPTS - 1) : (n0 + STEPS);
    xv[STEPS] = xrow[ib];  // clamped for last thread -> v=0 identity segment

    // uniform weights (scalar loads)
    float W1[8], B1[8], W2x[8], W2y[8];
#pragma unroll
    for (int c = 0; c < 8; ++c) {
        W1[c] = w1[c];
        B1[c] = b1[c];
        W2x[c] = w2[c];
        W2y[c] = w2[8 + c];
    }
    const float B2x = b2[0], B2y = b2[1];
    float WO[14];
#pragma unroll
    for (int i = 0; i < 14; ++i) WO[i] = wout[i];
    const float WO78 = WO[7] + WO[8];      // q_xy + q_yx share value
    const float WO1112 = WO[11] + WO[12];

    // ---- phase 1: increments + local chunk signature ----
    float vx[STEPS], vy[STEPS];
    float s[14];
#pragma unroll
    for (int i = 0; i < 14; ++i) s[i] = 0.0f;

    float ppx, ppy;
    augment(xv[0], W1, B1, W2x, W2y, B2x, B2y, ppx, ppy);
#pragma unroll
    for (int k = 0; k < STEPS; ++k) {
        float px, py;
        augment(xv[k + 1], W1, B1, W2x, W2y, B2x, B2y, px, py);
        vx[k] = px - ppx;
        vy[k] = py - ppy;
        ppx = px;
        ppy = py;
        chen_step(s, vx[k], vy[k]);
    }

    // ---- phase 2a: wave64 inclusive shuffle scan ----
#pragma unroll
    for (int off = 1; off < 64; off <<= 1) {
        float p[14];
#pragma unroll
        for (int i = 0; i < 14; ++i) p[i] = __shfl_up(s[i], (unsigned)off);
        if (lane >= off) chen_combine(p, s);
    }

    // ---- phase 2b: cross-wave combine (one barrier, broadcast read) ----
    if (t == 63) {
#pragma unroll
        for (int i = 0; i < 14; ++i) wsum[i] = s[i];
    }
    __syncthreads();

    float a[14];  // exclusive carry
    {
        float e[14];
#pragma unroll
        for (int i = 0; i < 14; ++i) e[i] = __shfl_up(s[i], 1u);
#pragma unroll
        for (int i = 0; i < 14; ++i) a[i] = (lane == 0) ? 0.0f : e[i];
    }
    if (wv == 1) {
        float tw[14];
#pragma unroll
        for (int i = 0; i < 14; ++i) tw[i] = wsum[i];
        chen_combine(tw, a);  // a = wave0_total ⊗ a  (identity-safe at lane 0)
    }

    // ---- phase 3: replay with level-3 folded into scalar z3 ----
    float z3 = WO[6] * a[6];
#pragma unroll
    for (int i = 7; i < 14; ++i) z3 = fmaf(WO[i], a[i], z3);
    float a1x = a[0], a1y = a[1];
    float a2xx = a[2], a2xy = a[3], a2yx = a[4], a2yy = a[5];

    float* __restrict__ orow = out + (size_t)brow * NSEG;
#pragma unroll
    for (int k = 0; k < STEPS; ++k) {
        const float vxk = vx[k], vyk = vy[k];
        const float qxx = 0.5f * vxk * vxk;
        const float qxy = 0.5f * vxk * vyk;
        const float qyy = 0.5f * vyk * vyk;
        const float wx = fmaf(vxk, (1.0f / 3.0f), a1x);
        const float wy = fmaf(vyk, (1.0f / 3.0f), a1y);
        // z3 += sum_ij a2_ij (WO3_ij . v)
        const float tvxx = fmaf(WO[7], vyk, WO[6] * vxk);
        const float tvxy = fmaf(WO[9], vyk, WO[8] * vxk);
        const float tvyx = fmaf(WO[11], vyk, WO[10] * vxk);
        const float tvyy = fmaf(WO[13], vyk, WO[12] * vxk);
        z3 = fmaf(a2xx, tvxx, z3);
        z3 = fmaf(a2xy, tvxy, z3);
        z3 = fmaf(a2yx, tvyx, z3);
        z3 = fmaf(a2yy, tvyy, z3);
        // z3 += sum_i w_i (WO3_i.. . q)
        const float tqx = fmaf(WO[9], qyy, fmaf(WO78, qxy, WO[6] * qxx));
        const float tqy = fmaf(WO[13], qyy, fmaf(WO1112, qxy, WO[10] * qxx));
        z3 = fmaf(wx, tqx, z3);
        z3 = fmaf(wy, tqy, z3);
        // level-2 / level-1 state updates
        const float ux = fmaf(vxk, 0.5f, a1x);
        const float uy = fmaf(vyk, 0.5f, a1y);
        a2xx = fmaf(ux, vxk, a2xx);
        a2xy = fmaf(ux, vyk, a2xy);
        a2yx = fmaf(uy, vxk, a2yx);
        a2yy = fmaf(uy, vyk, a2yy);
        a1x += vxk;
        a1y += vyk;
        // project
        float o = z3;
        o = fmaf(WO[0], a1x, o);
        o = fmaf(WO[1], a1y, o);
        o = fmaf(WO[2], a2xx, o);
        o = fmaf(WO[3], a2xy, o);
        o = fmaf(WO[4], a2yx, o);
        o = fmaf(WO[5], a2yy, o);
        const int n = n0 + k;
        if (n < NSEG) orow[n] = o;
    }
}

extern "C" void kernel_launch(void* const* d_in, const int* in_sizes, int n_in,
                              void* d_out, int out_size, void* d_ws, size_t ws_size,
                              hipStream_t stream) {
    const float* x  = (const float*)d_in[0];
    const float* w1 = (const float*)d_in[1];
    const float* b1 = (const float*)d_in[2];
    const float* w2 = (const float*)d_in[3];
    const float* b2 = (const float*)d_in[4];
    const float* wo = (const float*)d_in[5];
    float* out = (float*)d_out;
    sig_scan_kernel<<<NBATCH, TPR, 0, stream>>>(x, w1, b1, w2, b2, wo, out);
}

// Round 4
// 21.528 us; speedup vs baseline: 2.3515x; 2.3515x over previous
//
#include <hip/hip_runtime.h>

#define LPTS  2048   // points per row
#define NSEG  2047   // increments per row
#define TPB   256
#define STEPS 8      // segments per thread
#define NBATCH 2048
#define NWAVE (TPB / 64)

// Quotient signature state (7 floats): s[0]=a1x s[1]=a1y s[2]=a2xx s[3]=a2xy
// s[4]=a2yx s[5]=a2yy s[6]=z3 (= <WO3, a3>). Valid because a3 never feeds
// back into a1/a2 and the output only needs <WO3,a3>.

// s := s ⊗ sig(segment with increment v), z3-folded.
__device__ __forceinline__ void chen_step7(float s[7], float vx, float vy,
                                           const float WO[14], float WO78,
                                           float WO1112) {
    const float qxx = 0.5f * vx * vx;
    const float qxy = 0.5f * vx * vy;
    const float qyy = 0.5f * vy * vy;
    const float wx = fmaf(vx, (1.0f / 3.0f), s[0]);
    const float wy = fmaf(vy, (1.0f / 3.0f), s[1]);
    // z3 += sum_ij a2_ij (WO3_ij. · v)
    const float tvxx = fmaf(WO[7], vy, WO[6] * vx);
    const float tvxy = fmaf(WO[9], vy, WO[8] * vx);
    const float tvyx = fmaf(WO[11], vy, WO[10] * vx);
    const float tvyy = fmaf(WO[13], vy, WO[12] * vx);
    float z = s[6];
    z = fmaf(s[2], tvxx, z);
    z = fmaf(s[3], tvxy, z);
    z = fmaf(s[4], tvyx, z);
    z = fmaf(s[5], tvyy, z);
    // z3 += sum_i (a1_i + v_i/3) (WO3_i.. : q)   [covers a1⊗g2 and g3]
    const float tqx = fmaf(WO[9], qyy, fmaf(WO78, qxy, WO[6] * qxx));
    const float tqy = fmaf(WO[13], qyy, fmaf(WO1112, qxy, WO[10] * qxx));
    z = fmaf(wx, tqx, z);
    z = fmaf(wy, tqy, z);
    s[6] = z;
    // a2 += (a1 + 0.5 v) ⊗ v
    const float ux = fmaf(vx, 0.5f, s[0]);
    const float uy = fmaf(vy, 0.5f, s[1]);
    s[2] = fmaf(ux, vx, s[2]);
    s[3] = fmaf(ux, vy, s[3]);
    s[4] = fmaf(uy, vx, s[4]);
    s[5] = fmaf(uy, vy, s[5]);
    s[0] += vx;
    s[1] += vy;
}

// b := a ⊗ b (a earlier), quotiented Chen combine.
__device__ __forceinline__ void chen_combine7(const float a[7], float b[7],
                                              const float WO[14]) {
    // z: cross terms a2⊗b1 and a1⊗b2 projected onto WO3
    const float tvxx = fmaf(WO[7], b[1], WO[6] * b[0]);
    const float tvxy = fmaf(WO[9], b[1], WO[8] * b[0]);
    const float tvyx = fmaf(WO[11], b[1], WO[10] * b[0]);
    const float tvyy = fmaf(WO[13], b[1], WO[12] * b[0]);
    float z = a[6] + b[6];
    z = fmaf(a[2], tvxx, z);
    z = fmaf(a[3], tvxy, z);
    z = fmaf(a[4], tvyx, z);
    z = fmaf(a[5], tvyy, z);
    const float ubx = fmaf(WO[9], b[5], fmaf(WO[8], b[4], fmaf(WO[7], b[3], WO[6] * b[2])));
    const float uby = fmaf(WO[13], b[5], fmaf(WO[12], b[4], fmaf(WO[11], b[3], WO[10] * b[2])));
    z = fmaf(a[0], ubx, z);
    z = fmaf(a[1], uby, z);
    // a2 cross and sums
    const float cxx = a[2] + fmaf(a[0], b[0], b[2]);
    const float cxy = a[3] + fmaf(a[0], b[1], b[3]);
    const float cyx = a[4] + fmaf(a[1], b[0], b[4]);
    const float cyy = a[5] + fmaf(a[1], b[1], b[5]);
    b[0] = a[0] + b[0];
    b[1] = a[1] + b[1];
    b[2] = cxx;
    b[3] = cxy;
    b[4] = cyx;
    b[5] = cyy;
    b[6] = z;
}

// pointwise MLP 1 -> 8 -> 2 (ReLU between)
__device__ __forceinline__ void augment(float x,
                                        const float W1[8], const float B1[8],
                                        const float W2x[8], const float W2y[8],
                                        float B2x, float B2y,
                                        float& px, float& py) {
    float ox = B2x, oy = B2y;
#pragma unroll
    for (int c = 0; c < 8; ++c) {
        float h = fmaxf(fmaf(W1[c], x, B1[c]), 0.0f);
        ox = fmaf(W2x[c], h, ox);
        oy = fmaf(W2y[c], h, oy);
    }
    px = ox;
    py = oy;
}

__global__ __launch_bounds__(TPB) void sig_scan_kernel(
    const float* __restrict__ x, const float* __restrict__ w1,
    const float* __restrict__ b1, const float* __restrict__ w2,
    const float* __restrict__ b2, const float* __restrict__ wout,
    float* __restrict__ out) {
    __shared__ float wsum[NWAVE][8];  // per-wave 7-state totals

    const int t = threadIdx.x;
    const int lane = t & 63;
    const int wv = t >> 6;
    const int brow = blockIdx.x;
    const float* __restrict__ xrow = x + (size_t)brow * LPTS;

    // uniform weights -> scalar loads (SGPRs)
    float W1[8], B1[8], W2x[8], W2y[8];
#pragma unroll
    for (int c = 0; c < 8; ++c) {
        W1[c] = w1[c];
        B1[c] = b1[c];
        W2x[c] = w2[c];
        W2y[c] = w2[8 + c];
    }
    const float B2x = b2[0], B2y = b2[1];
    float WO[14];
#pragma unroll
    for (int i = 0; i < 14; ++i) WO[i] = wout[i];
    const float WO78 = WO[7] + WO[8];
    const float WO1112 = WO[11] + WO[12];

    // ---- phase 1: load points, augment, increments, local 7-state sig ----
    const int n0 = t * STEPS;
    const float4 xa = *reinterpret_cast<const float4*>(xrow + n0);
    const float4 xb = *reinterpret_cast<const float4*>(xrow + n0 + 4);
    const int ib = (n0 + STEPS > LPTS - 1) ? (LPTS - 1) : (n0 + STEPS);
    const float x8 = xrow[ib];  // clamped -> v=0 identity for last thread
    const float xv[STEPS + 1] = {xa.x, xa.y, xa.z, xa.w,
                                 xb.x, xb.y, xb.z, xb.w, x8};

    float vx[STEPS], vy[STEPS];
    float s[7] = {0, 0, 0, 0, 0, 0, 0};
    float ppx, ppy;
    augment(xv[0], W1, B1, W2x, W2y, B2x, B2y, ppx, ppy);
#pragma unroll
    for (int k = 0; k < STEPS; ++k) {
        float px, py;
        augment(xv[k + 1], W1, B1, W2x, W2y, B2x, B2y, px, py);
        vx[k] = px - ppx;
        vy[k] = py - ppy;
        ppx = px;
        ppy = py;
        chen_step7(s, vx[k], vy[k], WO, WO78, WO1112);
    }

    // ---- phase 2a: wave64 inclusive shuffle scan (7-wide) ----
#pragma unroll
    for (int off = 1; off < 64; off <<= 1) {
        float p[7];
#pragma unroll
        for (int i = 0; i < 7; ++i) p[i] = __shfl_up(s[i], (unsigned)off);
        if (lane >= off) chen_combine7(p, s, WO);
    }

    // ---- phase 2b: cross-wave combine (one barrier, broadcast reads) ----
    if (lane == 63) {
#pragma unroll
        for (int i = 0; i < 7; ++i) wsum[wv][i] = s[i];
    }
    __syncthreads();

    float a[7];  // exclusive carry
    {
        float e[7];
#pragma unroll
        for (int i = 0; i < 7; ++i) e[i] = __shfl_up(s[i], 1u);
#pragma unroll
        for (int i = 0; i < 7; ++i) a[i] = (lane == 0) ? 0.0f : e[i];
    }
    for (int w = wv - 1; w >= 0; --w) {
        float tw[7];
#pragma unroll
        for (int i = 0; i < 7; ++i) tw[i] = wsum[w][i];
        chen_combine7(tw, a, WO);
    }

    // ---- phase 3: replay with carry, project, direct store ----
    float* __restrict__ orow = out + (size_t)brow * NSEG;
#pragma unroll
    for (int k = 0; k < STEPS; ++k) {
        chen_step7(a, vx[k], vy[k], WO, WO78, WO1112);
        float o = a[6];
        o = fmaf(WO[0], a[0], o);
        o = fmaf(WO[1], a[1], o);
        o = fmaf(WO[2], a[2], o);
        o = fmaf(WO[3], a[3], o);
        o = fmaf(WO[4], a[4], o);
        o = fmaf(WO[5], a[5], o);
        const int n = n0 + k;
        if (n < NSEG) orow[n] = o;
    }
}

extern "C" void kernel_launch(void* const* d_in, const int* in_sizes, int n_in,
                              void* d_out, int out_size, void* d_ws, size_t ws_size,
                              hipStream_t stream) {
    const float* x  = (const float*)d_in[0];
    const float* w1 = (const float*)d_in[1];
    const float* b1 = (const float*)d_in[2];
    const float* w2 = (const float*)d_in[3];
    const float* b2 = (const float*)d_in[4];
    const float* wo = (const float*)d_in[5];
    float* out = (float*)d_out;
    sig_scan_kernel<<<NBATCH, TPB, 0, stream>>>(x, w1, b1, w2, b2, wo, out);
}